// Round 17
// baseline (782.222 us; speedup 1.0000x reference)
//
#include <hip/hip_runtime.h>
#include <hip/hip_bf16.h>
#include <cstdint>
#include <cstddef>
#include <cmath>

#define DEV __device__ __forceinline__

typedef __attribute__((ext_vector_type(8))) short bf16x8;
typedef __attribute__((ext_vector_type(4))) float f32x4;

// Abramowitz-Stegun 7.1.26 erf approx, |abs err| <= 1.5e-7
DEV float erf_fast(float x){
  float ax = fabsf(x);
  float t = __builtin_amdgcn_rcpf(fmaf(0.3275911f, ax, 1.f));
  float p = t*fmaf(t, fmaf(t, fmaf(t, fmaf(t, 1.061405429f, -1.453152027f),
             1.421413741f), -0.284496736f), 0.254829592f);
  float e = __expf(-ax*ax);
  float r = fmaf(-p, e, 1.f);
  return x >= 0.f ? r : -r;
}
DEV float gelu_f(float x){ return 0.5f*x*(1.0f + erf_fast(x*0.7071067811865476f)); }
DEV float softplus_f(float x){ return fmaxf(x,0.f) + log1pf(expf(-fabsf(x))); }
DEV unsigned short f2bf(float x){
  __hip_bfloat16 h = __float2bfloat16(x);
  return reinterpret_cast<unsigned short&>(h);
}
DEV float bf2f(unsigned short h){
  unsigned u = ((unsigned)h) << 16;
  return __uint_as_float(u);
}

// ---------------------------------------------------------------------------
// Combined weight packing: 8 jobs in one launch.
// ---------------------------------------------------------------------------
struct PackJobs {
  const float* src[8];
  unsigned short* dst[8];
  int ntn[8], ntk[8], K[8], conv[8], base[8];
};

__global__ __launch_bounds__(256) void packall_k(PackJobs J)
{
  int blk = blockIdx.x;
  int j = 0;
#pragma unroll
  for (int i=1;i<8;++i) if (blk >= J.base[i]) j = i;
  int tid = (blk - J.base[j])*256 + threadIdx.x;
  const int ntk = J.ntk[j], K = J.K[j];
  int total = J.ntn[j]*ntk*64;
  if (tid >= total) return;
  int lane = tid & 63;
  int f = tid >> 6;
  int kt = f % ntk, nt = f / ntk;
  int row = nt*16 + (lane & 15);
  int k0 = kt*32 + (lane >> 4)*8;
  const float* src = J.src[j];
  unsigned short h[8];
  if (J.conv[j]) {
    const int Cin = K;
#pragma unroll
    for (int q=0;q<8;++q) {
      int k = k0 + q;
      int s = k / Cin;
      int ic = k - s*Cin;
      h[q] = f2bf(src[((size_t)row*Cin + ic)*9 + s]);
    }
  } else {
#pragma unroll
    for (int q=0;q<8;++q) h[q] = f2bf(src[(size_t)row*K + k0 + q]);
  }
  uint4 pk;
  pk.x = (unsigned)h[0] | ((unsigned)h[1]<<16);
  pk.y = (unsigned)h[2] | ((unsigned)h[3]<<16);
  pk.z = (unsigned)h[4] | ((unsigned)h[5]<<16);
  pk.w = (unsigned)h[6] | ((unsigned)h[7]<<16);
  *reinterpret_cast<uint4*>(J.dst[j] + (size_t)tid*8) = pk;
}

// dw weight transpose: wT[k][ch] = w[ch][k]  (49 x 256)
__global__ __launch_bounds__(256) void dwt_k(const float* __restrict__ w,
                                             float* __restrict__ wT)
{
  int k = blockIdx.x;
  int ch = threadIdx.x;
  wT[k*256 + ch] = w[(size_t)ch*49 + k];
}

// ---------------------------------------------------------------------------
// Extract clamped 33x33 vis windows (incl. conv zero ring) -> bf16 NHWC
// ---------------------------------------------------------------------------
__global__ __launch_bounds__(256) void extvwin_k(const float* __restrict__ vis,
                                                 const float* __restrict__ spv,
                                                 unsigned short* __restrict__ vwin)
{
  int il = blockIdx.x;
  int p = blockIdx.y*256 + threadIdx.x;
  if (p >= 1089) return;
  int wy = p/33, wx = p%33;
  unsigned short* dst = vwin + ((size_t)il*1089 + p)*64;
  if (wy==0 || wy==32 || wx==0 || wx==32) {
    uint4 z = {0,0,0,0};
#pragma unroll
    for (int q=0;q<8;++q) *reinterpret_cast<uint4*>(dst + q*8) = z;
    return;
  }
  int cx = (int)rintf(spv[il*2+0]);
  int cy = (int)rintf(spv[il*2+1]);
  int gy = min(max(cy + wy - 16, 0), 1023);
  int gx = min(max(cx + wx - 16, 0), 1023);
  const float* sp = vis + (size_t)gy*1024 + gx;
  unsigned short h[64];
#pragma unroll
  for (int c=0;c<64;++c) h[c] = f2bf(sp[(size_t)c<<20]);
#pragma unroll
  for (int q=0;q<8;++q) {
    uint4 pk;
    pk.x = (unsigned)h[q*8+0] | ((unsigned)h[q*8+1]<<16);
    pk.y = (unsigned)h[q*8+2] | ((unsigned)h[q*8+3]<<16);
    pk.z = (unsigned)h[q*8+4] | ((unsigned)h[q*8+5]<<16);
    pk.w = (unsigned)h[q*8+6] | ((unsigned)h[q*8+7]<<16);
    *reinterpret_cast<uint4*>(dst + q*8) = pk;
  }
}

// ---------------------------------------------------------------------------
// Fused intrinsic conv chain, 4-row output strips.
// bufIn: 10x33 rows x64 (win rows y0-2..y0+7); bufC1: 8x33 (c1 rows y0-2..y0+5);
// bufC2 aliases bufIn (6x33, c2 rows y0-1..y0+4). c3 out rows y0..y0+3.
// LDS 76 KB -> 2 blocks/CU. launch_bounds(512,2) -> VGPR cap 128 (no spill).
// ---------------------------------------------------------------------------
__global__ __launch_bounds__(512,2) void convchain4_k(
    const unsigned short* __restrict__ vwin,
    const unsigned short* __restrict__ Wp1, const float* __restrict__ B1,
    const unsigned short* __restrict__ Wp2, const float* __restrict__ B2,
    const unsigned short* __restrict__ Wp3, const float* __restrict__ B3,
    unsigned short* __restrict__ outI)
{
  const int item = blockIdx.x;
  const int y0 = blockIdx.y*4;
  const int t = threadIdx.x;
  const int w = t>>6, l = t&63, g = l>>4, l15 = l&15;

  __shared__ __align__(16) unsigned short bufIn[330*64];   // 42,240 B
  __shared__ __align__(16) unsigned short bufC1[264*64];   // 33,792 B
  unsigned short* bufC2 = bufIn;                           // 198*64 needed

  const uint4 z4 = {0,0,0,0};

  // zero bufC1 + stage bufIn
  for (int u=t; u<264*8; u+=512)
    *reinterpret_cast<uint4*>(bufC1 + u*8) = z4;
  for (int u=t; u<330*8; u+=512) {
    int slot = u & 7;
    int rowi = u >> 3;              // r*33+col, r in 0..9
    int r = rowi/33;
    int wy = y0 - 2 + r;
    uint4 val = z4;
    if ((unsigned)wy < 33u)
      val = *reinterpret_cast<const uint4*>(
          vwin + ((size_t)item*1089 + wy*33 + (rowi - r*33))*64 + slot*8);
    int ds = slot ^ (rowi & 7);
    *reinterpret_cast<uint4*>(&bufIn[rowi*64 + ds*8]) = val;
  }
  __syncthreads();

  // ---- c1: 8 rows x 31 (248 pos, 16 tiles, 2/wave), gelu -> bufC1 ----
  {
    int pbase[2], rowB[2]; bool pv[2];
#pragma unroll
    for (int pt=0; pt<2; ++pt) {
      int pd = (w*2+pt)*16 + l15;
      int pc = min(pd, 247);
      int ry = pc/31, rx = pc - ry*31;
      pbase[pt] = ry*33 + rx;
      rowB[pt] = ry*33 + rx + 1;
      int yab = y0 - 2 + ry;
      pv[pt] = (pd < 248) && ((unsigned)yab < 31u);
    }
    f32x4 a1[4][2];
#pragma unroll
    for (int o=0;o<4;++o)
#pragma unroll
      for (int pt=0;pt<2;++pt) a1[o][pt] = (f32x4){0.f,0.f,0.f,0.f};

    for (int kt=0; kt<18; ++kt) {
      int k0 = kt*32 + g*8;
      int s = k0 >> 6;
      int icg = (k0 - (s<<6)) >> 3;
      int roff = (s/3)*33 + (s - (s/3)*3);
      bf16x8 bf[2];
#pragma unroll
      for (int pt=0; pt<2; ++pt) {
        int rowi = pbase[pt] + roff;
        int ds = icg ^ (rowi & 7);
        bf[pt] = *reinterpret_cast<const bf16x8*>(&bufIn[rowi*64 + ds*8]);
      }
#pragma unroll
      for (int o=0; o<4; ++o) {
        bf16x8 af = *reinterpret_cast<const bf16x8*>(Wp1 + ((size_t)(o*18+kt)*64 + l)*8);
#pragma unroll
        for (int pt=0; pt<2; ++pt)
          a1[o][pt] = __builtin_amdgcn_mfma_f32_16x16x32_bf16(af, bf[pt], a1[o][pt], 0,0,0);
      }
    }
#pragma unroll
    for (int o=0; o<4; ++o) {
      float4 bv4 = *reinterpret_cast<const float4*>(B1 + o*16 + g*4);
      int sl = o*2 + (g>>1);
#pragma unroll
      for (int pt=0; pt<2; ++pt) {
        if (!pv[pt]) continue;
        float v0 = gelu_f(a1[o][pt][0] + bv4.x);
        float v1 = gelu_f(a1[o][pt][1] + bv4.y);
        float v2 = gelu_f(a1[o][pt][2] + bv4.z);
        float v3 = gelu_f(a1[o][pt][3] + bv4.w);
        uint2 pk;
        pk.x = (unsigned)f2bf(v0) | ((unsigned)f2bf(v1)<<16);
        pk.y = (unsigned)f2bf(v2) | ((unsigned)f2bf(v3)<<16);
        int phys = sl ^ (rowB[pt] & 7);
        *reinterpret_cast<uint2*>(&bufC1[rowB[pt]*64 + phys*8 + (g&1)*4]) = pk;
      }
    }
  }
  __syncthreads();

  // zero bufC2 (aliases bufIn; c1 reads done)
  for (int u=t; u<198*8; u+=512)
    *reinterpret_cast<uint4*>(bufC2 + u*8) = z4;
  __syncthreads();

  // ---- c2: 6 rows x 31 (186 pos, 12 tiles, 2/wave w/ mask), gelu -> bufC2 ----
  {
    int pbase[2], rowB[2]; bool pv[2];
#pragma unroll
    for (int pt=0; pt<2; ++pt) {
      int pd = (w*2+pt)*16 + l15;
      int pc = min(pd, 185);
      int ry = pc/31, rx = pc - ry*31;
      pbase[pt] = ry*33 + rx;
      rowB[pt] = ry*33 + rx + 1;
      int yab = y0 - 1 + ry;
      pv[pt] = (pd < 186) && ((unsigned)yab < 31u);
    }
    f32x4 a2[4][2];
#pragma unroll
    for (int o=0;o<4;++o)
#pragma unroll
      for (int pt=0;pt<2;++pt) a2[o][pt] = (f32x4){0.f,0.f,0.f,0.f};

    for (int kt=0; kt<18; ++kt) {
      int k0 = kt*32 + g*8;
      int s = k0 >> 6;
      int icg = (k0 - (s<<6)) >> 3;
      int roff = (s/3)*33 + (s - (s/3)*3);
      bf16x8 bf[2];
#pragma unroll
      for (int pt=0; pt<2; ++pt) {
        int rowi = pbase[pt] + roff;
        int ds = icg ^ (rowi & 7);
        bf[pt] = *reinterpret_cast<const bf16x8*>(&bufC1[rowi*64 + ds*8]);
      }
#pragma unroll
      for (int o=0; o<4; ++o) {
        bf16x8 af = *reinterpret_cast<const bf16x8*>(Wp2 + ((size_t)(o*18+kt)*64 + l)*8);
#pragma unroll
        for (int pt=0; pt<2; ++pt)
          a2[o][pt] = __builtin_amdgcn_mfma_f32_16x16x32_bf16(af, bf[pt], a2[o][pt], 0,0,0);
      }
    }
#pragma unroll
    for (int o=0; o<4; ++o) {
      float4 bv4 = *reinterpret_cast<const float4*>(B2 + o*16 + g*4);
      int sl = o*2 + (g>>1);
#pragma unroll
      for (int pt=0; pt<2; ++pt) {
        if (!pv[pt]) continue;
        float v0 = gelu_f(a2[o][pt][0] + bv4.x);
        float v1 = gelu_f(a2[o][pt][1] + bv4.y);
        float v2 = gelu_f(a2[o][pt][2] + bv4.z);
        float v3 = gelu_f(a2[o][pt][3] + bv4.w);
        uint2 pk;
        pk.x = (unsigned)f2bf(v0) | ((unsigned)f2bf(v1)<<16);
        pk.y = (unsigned)f2bf(v2) | ((unsigned)f2bf(v3)<<16);
        int phys = sl ^ (rowB[pt] & 7);
        *reinterpret_cast<uint2*>(&bufC2[rowB[pt]*64 + phys*8 + (g&1)*4]) = pk;
      }
    }
  }
  __syncthreads();

  // ---- c3: 4 rows x 31 (124 pos, 8 tiles, 1/wave w/ mask) -> global bf16 ----
  {
    int pd = w*16 + l15;
    int pc = min(pd, 123);
    int ry = pc/31, rx = pc - ry*31;
    int pbase = ry*33 + rx;
    int gpos = y0*31 + pd;
    bool pv = (pd < 124) && (gpos < 961) && (w < 8);

    f32x4 a3[2];
#pragma unroll
    for (int o=0;o<2;++o) a3[o] = (f32x4){0.f,0.f,0.f,0.f};

    if (w < 8) {
      for (int kt=0; kt<18; ++kt) {
        int k0 = kt*32 + g*8;
        int s = k0 >> 6;
        int icg = (k0 - (s<<6)) >> 3;
        int roff = (s/3)*33 + (s - (s/3)*3);
        int rowi = pbase + roff;
        int ds = icg ^ (rowi & 7);
        bf16x8 bf = *reinterpret_cast<const bf16x8*>(&bufC2[rowi*64 + ds*8]);
#pragma unroll
        for (int o=0; o<2; ++o) {
          bf16x8 af = *reinterpret_cast<const bf16x8*>(Wp3 + ((size_t)(o*18+kt)*64 + l)*8);
          a3[o] = __builtin_amdgcn_mfma_f32_16x16x32_bf16(af, bf, a3[o], 0,0,0);
        }
      }
    }
    if (pv) {
#pragma unroll
      for (int o=0; o<2; ++o) {
        float4 bv4 = *reinterpret_cast<const float4*>(B3 + o*16 + g*4);
        float v0 = a3[o][0] + bv4.x;
        float v1 = a3[o][1] + bv4.y;
        float v2 = a3[o][2] + bv4.z;
        float v3 = a3[o][3] + bv4.w;
        uint2 pk;
        pk.x = (unsigned)f2bf(v0) | ((unsigned)f2bf(v1)<<16);
        pk.y = (unsigned)f2bf(v2) | ((unsigned)f2bf(v3)<<16);
        *reinterpret_cast<uint2*>(outI + ((size_t)item*961 + gpos)*32 + o*16 + g*4) = pk;
      }
    }
  }
}

// ---------------------------------------------------------------------------
// Fused decoder v3: 16-row strips, 512 threads, channel-major LDS planes,
// FiLM+gelu staging, wave-level sum reduce.
// ---------------------------------------------------------------------------
__global__ __launch_bounds__(512,4) void decfused3_k(
    const unsigned short* __restrict__ intc,
    const unsigned short* __restrict__ Wp1, const float* __restrict__ B1,
    const unsigned short* __restrict__ Wp2, const float* __restrict__ B2,
    const float* __restrict__ film,
    const float* __restrict__ w3, const float* __restrict__ b3,
    float* __restrict__ outf, float* __restrict__ sums)
{
  const int item = blockIdx.x;
  const int y0 = blockIdx.y*16;
  const int t = threadIdx.x;
  const int w = t>>6, l = t&63, g = l>>4, l15 = l&15;

  constexpr int PA = 660;
  constexpr int PB = 594;
  __shared__ __align__(16) unsigned short ldsA[4*PA*8];
  __shared__ __align__(16) unsigned short ldsB[4*PB*8];

  const int sit = item >> 2;
  const float* frow = film + (size_t)item*64;

  for (int u=t; u<4*PB; u+=512)
    *reinterpret_cast<uint4*>(ldsB + u*8) = (uint4){0,0,0,0};

  for (int u=t; u<PA*4; u+=512) {
    int slot = u & 3;
    int rowi = u >> 2;
    int r = rowi/33, col = rowi - r*33;
    int y = y0 + r - 2, x = col - 1;
    uint4 val = {0,0,0,0};
    if ((unsigned)y < 31u && (unsigned)x < 31u) {
      val = *reinterpret_cast<const uint4*>(intc + ((size_t)sit*961 + y*31 + x)*32 + slot*8);
      int c0 = slot*8;
      float4 g0 = *reinterpret_cast<const float4*>(frow + c0);
      float4 g1 = *reinterpret_cast<const float4*>(frow + c0 + 4);
      float4 b0 = *reinterpret_cast<const float4*>(frow + 32 + c0);
      float4 b1 = *reinterpret_cast<const float4*>(frow + 32 + c0 + 4);
      unsigned short x8[8] = {
        (unsigned short)(val.x&0xffff),(unsigned short)(val.x>>16),
        (unsigned short)(val.y&0xffff),(unsigned short)(val.y>>16),
        (unsigned short)(val.z&0xffff),(unsigned short)(val.z>>16),
        (unsigned short)(val.w&0xffff),(unsigned short)(val.w>>16)};
      unsigned short o8[8];
      o8[0]=f2bf(gelu_f(fmaf(bf2f(x8[0]), 1.f+g0.x, b0.x)));
      o8[1]=f2bf(gelu_f(fmaf(bf2f(x8[1]), 1.f+g0.y, b0.y)));
      o8[2]=f2bf(gelu_f(fmaf(bf2f(x8[2]), 1.f+g0.z, b0.z)));
      o8[3]=f2bf(gelu_f(fmaf(bf2f(x8[3]), 1.f+g0.w, b0.w)));
      o8[4]=f2bf(gelu_f(fmaf(bf2f(x8[4]), 1.f+g1.x, b1.x)));
      o8[5]=f2bf(gelu_f(fmaf(bf2f(x8[5]), 1.f+g1.y, b1.y)));
      o8[6]=f2bf(gelu_f(fmaf(bf2f(x8[6]), 1.f+g1.z, b1.z)));
      o8[7]=f2bf(gelu_f(fmaf(bf2f(x8[7]), 1.f+g1.w, b1.w)));
      val.x = (unsigned)o8[0] | ((unsigned)o8[1]<<16);
      val.y = (unsigned)o8[2] | ((unsigned)o8[3]<<16);
      val.z = (unsigned)o8[4] | ((unsigned)o8[5]<<16);
      val.w = (unsigned)o8[6] | ((unsigned)o8[7]<<16);
    }
    *reinterpret_cast<uint4*>(&ldsA[((size_t)slot*PA + rowi)*8]) = val;
  }
  __syncthreads();

  // ---- dec1 ----
  {
    int pbase[5], rowB[5]; bool pv[5];
#pragma unroll
    for (int pt=0; pt<5; ++pt) {
      int pd = (w*5+pt)*16 + l15;
      int pc = min(pd, 557);
      int ry = pc/31, rx = pc - ry*31;
      pbase[pt] = ry*33 + rx;
      rowB[pt] = ry*33 + rx + 1;
      int gy = y0 - 1 + ry;
      pv[pt] = (pd < 558) && ((unsigned)gy < 31u);
    }
    f32x4 a1[2][5];
#pragma unroll
    for (int o=0;o<2;++o)
#pragma unroll
      for (int pt=0;pt<5;++pt) a1[o][pt] = (f32x4){0.f,0.f,0.f,0.f};

    for (int kt=0; kt<9; ++kt) {
      int roff = (kt/3)*33 + (kt - (kt/3)*3);
      bf16x8 bf[5];
#pragma unroll
      for (int pt=0; pt<5; ++pt) {
        int rowi = pbase[pt] + roff;
        bf[pt] = *reinterpret_cast<const bf16x8*>(&ldsA[((size_t)g*PA + rowi)*8]);
      }
#pragma unroll
      for (int o=0; o<2; ++o) {
        bf16x8 af = *reinterpret_cast<const bf16x8*>(Wp1 + ((size_t)(o*9+kt)*64 + l)*8);
#pragma unroll
        for (int pt=0; pt<5; ++pt)
          a1[o][pt] = __builtin_amdgcn_mfma_f32_16x16x32_bf16(af, bf[pt], a1[o][pt], 0,0,0);
      }
    }
#pragma unroll
    for (int o=0; o<2; ++o) {
      float4 bv4 = *reinterpret_cast<const float4*>(B1 + o*16 + g*4);
      int sl = o*2 + (g>>1);
#pragma unroll
      for (int pt=0; pt<5; ++pt) {
        if (!pv[pt]) continue;
        float v0 = gelu_f(a1[o][pt][0] + bv4.x);
        float v1 = gelu_f(a1[o][pt][1] + bv4.y);
        float v2 = gelu_f(a1[o][pt][2] + bv4.z);
        float v3 = gelu_f(a1[o][pt][3] + bv4.w);
        uint2 pk;
        pk.x = (unsigned)f2bf(v0) | ((unsigned)f2bf(v1)<<16);
        pk.y = (unsigned)f2bf(v2) | ((unsigned)f2bf(v3)<<16);
        *reinterpret_cast<uint2*>(&ldsB[((size_t)sl*PB + rowB[pt])*8 + (g&1)*4]) = pk;
      }
    }
  }
  __syncthreads();

  // ---- dec2 + gelu + dec3(1x1) + softplus + per-map sum ----
  float bsum = 0.f;
  {
    int pbase[4], gpos[4]; bool pv[4];
#pragma unroll
    for (int pt=0; pt<4; ++pt) {
      int pd = (w*4+pt)*16 + l15;
      int pc = min(pd, 495);
      int py = pc/31, px = pc - py*31;
      pbase[pt] = py*33 + px;
      gpos[pt] = y0*31 + pd;
      pv[pt] = (pd < 496) && (gpos[pt] < 961);
    }
    f32x4 a2[2][4];
#pragma unroll
    for (int o=0;o<2;++o)
#pragma unroll
      for (int pt=0;pt<4;++pt) a2[o][pt] = (f32x4){0.f,0.f,0.f,0.f};

    for (int kt=0; kt<9; ++kt) {
      int roff = (kt/3)*33 + (kt - (kt/3)*3);
      bf16x8 bf[4];
#pragma unroll
      for (int pt=0; pt<4; ++pt) {
        int rowi = pbase[pt] + roff;
        bf[pt] = *reinterpret_cast<const bf16x8*>(&ldsB[((size_t)g*PB + rowi)*8]);
      }
#pragma unroll
      for (int o=0; o<2; ++o) {
        bf16x8 af = *reinterpret_cast<const bf16x8*>(Wp2 + ((size_t)(o*9+kt)*64 + l)*8);
#pragma unroll
        for (int pt=0; pt<4; ++pt)
          a2[o][pt] = __builtin_amdgcn_mfma_f32_16x16x32_bf16(af, bf[pt], a2[o][pt], 0,0,0);
      }
    }

    float w3r[8];
#pragma unroll
    for (int o=0;o<2;++o) {
      float4 wv = *reinterpret_cast<const float4*>(w3 + o*16 + g*4);
      w3r[o*4+0]=wv.x; w3r[o*4+1]=wv.y; w3r[o*4+2]=wv.z; w3r[o*4+3]=wv.w;
    }
    float b3v = b3[0];
#pragma unroll
    for (int pt=0; pt<4; ++pt) {
      float part = 0.f;
#pragma unroll
      for (int o=0; o<2; ++o) {
        float4 bv4 = *reinterpret_cast<const float4*>(B2 + o*16 + g*4);
        float v0 = gelu_f(a2[o][pt][0] + bv4.x);
        float v1 = gelu_f(a2[o][pt][1] + bv4.y);
        float v2 = gelu_f(a2[o][pt][2] + bv4.z);
        float v3 = gelu_f(a2[o][pt][3] + bv4.w);
        part += v0*w3r[o*4+0] + v1*w3r[o*4+1] + v2*w3r[o*4+2] + v3*w3r[o*4+3];
      }
      part += __shfl_xor(part, 16);
      part += __shfl_xor(part, 32);
      float sp = softplus_f(part + b3v);
      if (pv[pt] && g==0) {
        outf[(size_t)item*961 + gpos[pt]] = sp;
        bsum += sp;
      }
    }
  }
  bsum += __shfl_xor(bsum, 1);
  bsum += __shfl_xor(bsum, 2);
  bsum += __shfl_xor(bsum, 4);
  bsum += __shfl_xor(bsum, 8);
  bsum += __shfl_xor(bsum, 16);
  bsum += __shfl_xor(bsum, 32);
  if (l == 0) atomicAdd(&sums[item], bsum);
}

// ---------------------------------------------------------------------------
// Fused bottleneck-window gather + depthwise 7x7, channel-sliced, row-reuse.
// ---------------------------------------------------------------------------
__global__ __launch_bounds__(256,4) void dwfused4_k(
    const float* __restrict__ bott, const float* __restrict__ spv,
    const float* __restrict__ wT, const float* __restrict__ b,
    unsigned short* __restrict__ bwinT, unsigned short* __restrict__ dwout)
{
  const int n = blockIdx.x, cs = blockIdx.y*64, t = threadIdx.x;
  __shared__ float tile[121*66];

  float pxf = fminf(fmaxf(spv[n*2+0]*0.25f, 0.f), 255.f);
  float pyf = fminf(fmaxf(spv[n*2+1]*0.25f, 0.f), 255.f);
  int cx = (int)rintf(pxf), cy = (int)rintf(pyf);

  for (int idx=t; idx<121*32; idx+=256) {
    int j = idx/121, p = idx - j*121;
    int y = p/11, x = p - y*11;
    int gy = min(max(cy + y - 5, 0), 255);
    int gx = min(max(cx + x - 5, 0), 255);
    const float* s0 = bott + ((size_t)(cs+2*j)<<16) + (gy<<8) + gx;
    *reinterpret_cast<float2*>(&tile[p*66 + 2*j]) = (float2){s0[0], s0[65536]};
  }
  __syncthreads();

  for (int idx=t; idx<121*64; idx+=256) {
    int p = idx >> 6, c = idx & 63;
    bwinT[((size_t)n*121 + p)*256 + cs + c] = f2bf(tile[p*66 + c]);
  }

  const int c = t & 63, ph = t >> 6;
  const int ch = cs + c;
  const float bias = b[ch];

  for (int y=ph; y<11; y+=4) {
    float acc[11];
#pragma unroll
    for (int x=0;x<11;++x) acc[x] = bias;
#pragma unroll
    for (int dy=0; dy<7; ++dy) {
      int yy = y + dy - 3;
      if ((unsigned)yy < 11u) {
        float r[11];
#pragma unroll
        for (int k=0;k<11;++k) r[k] = tile[(yy*11+k)*66 + c];
        float w7[7];
#pragma unroll
        for (int j=0;j<7;++j) w7[j] = wT[(dy*7+j)*256 + ch];
#pragma unroll
        for (int x=0;x<11;++x) {
#pragma unroll
          for (int dx=0;dx<7;++dx) {
            int xx = x + dx - 3;
            if (xx >= 0 && xx < 11)
              acc[x] = fmaf(r[xx], w7[dx], acc[x]);
          }
        }
      }
    }
#pragma unroll
    for (int x=0;x<11;++x)
      dwout[((size_t)n*121 + y*11 + x)*256 + ch] = f2bf(acc[x]);
  }
}

// ---------------------------------------------------------------------------
// Fused ConvNeXt MLP + bnp head, bf16 MFMA. 512 threads / 8 waves, 64 rows.
// ---------------------------------------------------------------------------
__global__ __launch_bounds__(512,4) void cnx_mfma3_k(
    const unsigned short* __restrict__ xin,
    const float* __restrict__ lnw, const float* __restrict__ lnb,
    const unsigned short* __restrict__ W1p, const float* __restrict__ B1,
    const unsigned short* __restrict__ W2p, const float* __restrict__ B2,
    const float* __restrict__ gvec,
    const unsigned short* __restrict__ bwinT,
    const unsigned short* __restrict__ Wbp, const float* __restrict__ bnpb,
    float* __restrict__ bnv, float inv_gsum)
{
  const int t = threadIdx.x;
  const int w = t >> 6;
  const int l = t & 63;
  const int g = l >> 4;
  const int l15 = l & 15;
  const int row0 = blockIdx.x * 64;

  __shared__ __align__(16) unsigned short xs[64*264];
  __shared__ __align__(16) unsigned short hs[64*136];

  {
    const int rl = t >> 3, q = t & 7;
    const unsigned short* xr = xin + (size_t)(row0+rl)*256 + q*32;
    float xv[32]; float s = 0.f, s2 = 0.f;
#pragma unroll
    for (int i=0;i<32;i+=8){
      uint4 v = *reinterpret_cast<const uint4*>(xr+i);
      unsigned short xh[8] = {
        (unsigned short)(v.x&0xffff),(unsigned short)(v.x>>16),
        (unsigned short)(v.y&0xffff),(unsigned short)(v.y>>16),
        (unsigned short)(v.z&0xffff),(unsigned short)(v.z>>16),
        (unsigned short)(v.w&0xffff),(unsigned short)(v.w>>16)};
#pragma unroll
      for (int j=0;j<8;++j){
        float f = bf2f(xh[j]);
        xv[i+j] = f; s += f; s2 += f*f;
      }
    }
    s += __shfl_xor(s,1); s2 += __shfl_xor(s2,1);
    s += __shfl_xor(s,2); s2 += __shfl_xor(s2,2);
    s += __shfl_xor(s,4); s2 += __shfl_xor(s2,4);
    float mu = s*(1.f/256.f);
    float rstd = rsqrtf(s2*(1.f/256.f) - mu*mu + 1e-6f);
#pragma unroll
    for (int i=0;i<32;i+=8){
      int c = q*32 + i;
      float4 w0 = *reinterpret_cast<const float4*>(lnw+c);
      float4 w1 = *reinterpret_cast<const float4*>(lnw+c+4);
      float4 b0 = *reinterpret_cast<const float4*>(lnb+c);
      float4 b1 = *reinterpret_cast<const float4*>(lnb+c+4);
      unsigned short h[8];
      h[0]=f2bf(fmaf((xv[i+0]-mu)*rstd, w0.x, b0.x));
      h[1]=f2bf(fmaf((xv[i+1]-mu)*rstd, w0.y, b0.y));
      h[2]=f2bf(fmaf((xv[i+2]-mu)*rstd, w0.z, b0.z));
      h[3]=f2bf(fmaf((xv[i+3]-mu)*rstd, w0.w, b0.w));
      h[4]=f2bf(fmaf((xv[i+4]-mu)*rstd, w1.x, b1.x));
      h[5]=f2bf(fmaf((xv[i+5]-mu)*rstd, w1.y, b1.y));
      h[6]=f2bf(fmaf((xv[i+6]-mu)*rstd, w1.z, b1.z));
      h[7]=f2bf(fmaf((xv[i+7]-mu)*rstd, w1.w, b1.w));
      uint4 pk;
      pk.x = (unsigned)h[0] | ((unsigned)h[1]<<16);
      pk.y = (unsigned)h[2] | ((unsigned)h[3]<<16);
      pk.z = (unsigned)h[4] | ((unsigned)h[5]<<16);
      pk.w = (unsigned)h[6] | ((unsigned)h[7]<<16);
      *reinterpret_cast<uint4*>(&xs[rl*264 + c]) = pk;
    }
  }
  __syncthreads();

  f32x4 acc2[8];
#pragma unroll
  for (int i=0;i<8;++i) acc2[i] = (f32x4){0.f,0.f,0.f,0.f};

  for (int hc=0; hc<8; ++hc) {
    const int ht = hc*8 + w;
    f32x4 acc1[4];
#pragma unroll
    for (int i=0;i<4;++i) acc1[i] = (f32x4){0.f,0.f,0.f,0.f};

#pragma unroll
    for (int kt=0; kt<8; ++kt) {
      bf16x8 xf[4];
#pragma unroll
      for (int rt=0; rt<4; ++rt)
        xf[rt] = *reinterpret_cast<const bf16x8*>(&xs[(rt*16+l15)*264 + kt*32 + g*8]);
      bf16x8 wf = *reinterpret_cast<const bf16x8*>(W1p + ((size_t)(ht*8+kt)*64 + l)*8);
#pragma unroll
      for (int rt=0; rt<4; ++rt)
        acc1[rt] = __builtin_amdgcn_mfma_f32_16x16x32_bf16(wf, xf[rt], acc1[rt], 0,0,0);
    }
    {
      const int hb = hc*128 + w*16 + 4*g;
      float4 b1v = *reinterpret_cast<const float4*>(B1 + hb);
#pragma unroll
      for (int rt=0; rt<4; ++rt) {
        unsigned short h0 = f2bf(gelu_f(acc1[rt][0] + b1v.x));
        unsigned short h1 = f2bf(gelu_f(acc1[rt][1] + b1v.y));
        unsigned short h2 = f2bf(gelu_f(acc1[rt][2] + b1v.z));
        unsigned short h3 = f2bf(gelu_f(acc1[rt][3] + b1v.w));
        uint2 pk;
        pk.x = (unsigned)h0 | ((unsigned)h1<<16);
        pk.y = (unsigned)h2 | ((unsigned)h3<<16);
        *reinterpret_cast<uint2*>(&hs[(rt*16+l15)*136 + w*16 + 4*g]) = pk;
      }
    }
    __syncthreads();
#pragma unroll
    for (int kt=0; kt<4; ++kt) {
      bf16x8 hf[4];
#pragma unroll
      for (int rt=0; rt<4; ++rt)
        hf[rt] = *reinterpret_cast<const bf16x8*>(&hs[(rt*16+l15)*136 + kt*32 + g*8]);
#pragma unroll
      for (int cj=0; cj<2; ++cj) {
        const int ct = 2*w + cj;
        bf16x8 wf = *reinterpret_cast<const bf16x8*>(W2p + ((size_t)(ct*32 + hc*4 + kt)*64 + l)*8);
#pragma unroll
        for (int rt=0; rt<4; ++rt)
          acc2[cj*4+rt] = __builtin_amdgcn_mfma_f32_16x16x32_bf16(hf[rt], wf, acc2[cj*4+rt], 0,0,0);
      }
    }
    __syncthreads();
  }

#pragma unroll
  for (int cj=0; cj<2; ++cj) {
    const int c = (2*w+cj)*16 + l15;
    const float b2 = B2[c], gm = gvec[c];
#pragma unroll
    for (int rt=0; rt<4; ++rt) {
#pragma unroll
      for (int reg=0; reg<4; ++reg) {
        int row = rt*16 + 4*g + reg;
        float res = bf2f(bwinT[(size_t)(row0+row)*256 + c]) + (acc2[cj*4+rt][reg] + b2)*gm;
        xs[row*264 + c] = f2bf(res);
      }
    }
  }
  __syncthreads();

  {
    const int oct = w & 3;
    f32x4 abn[2];
#pragma unroll
    for (int i=0;i<2;++i) abn[i] = (f32x4){0.f,0.f,0.f,0.f};
#pragma unroll
    for (int kt=0; kt<8; ++kt) {
      bf16x8 bfw = *reinterpret_cast<const bf16x8*>(Wbp + ((size_t)(oct*8+kt)*64 + l)*8);
#pragma unroll
      for (int i=0;i<2;++i) {
        const int rt = (w>>2) + 2*i;
        bf16x8 af = *reinterpret_cast<const bf16x8*>(&xs[(rt*16+l15)*264 + kt*32 + g*8]);
        abn[i] = __builtin_amdgcn_mfma_f32_16x16x32_bf16(af, bfw, abn[i], 0,0,0);
      }
    }

    float* red = reinterpret_cast<float*>(hs);
#pragma unroll
    for (int i=0;i<2;++i) {
      const int rt = (w>>2) + 2*i;
      float bv = bnpb[oct*16 + l15];
#pragma unroll
      for (int reg=0; reg<4; ++reg) {
        int lr = rt*16 + g*4 + reg;
        int p = (row0 + lr) % 121;
        int py=p/11, px=p-py*11;
        float ly=-1.f+0.2f*py, lx=-1.f+0.2f*px;
        float wg = __expf(-(lx*lx+ly*ly)/0.32f) * inv_gsum;
        red[lr*64 + oct*16 + l15] = gelu_f(abn[i][reg] + bv) * wg;
      }
    }
  }
  __syncthreads();
  {
    float* red = reinterpret_cast<float*>(hs);
    int oc = t & 63, seg = t >> 6;
    float s = 0.f;
    int curn = (row0 + seg*8) / 121;
    for (int i=0;i<8;++i) {
      int row = seg*8 + i;
      int n = (row0 + row) / 121;
      if (n != curn) { atomicAdd(&bnv[curn*64 + oc], s); s = 0.f; curn = n; }
      s += red[row*64 + oc];
    }
    atomicAdd(&bnv[curn*64 + oc], s);
  }
}

// ---------------------------------------------------------------------------
// FiLM
// ---------------------------------------------------------------------------
__global__ __launch_bounds__(256) void film_k(
    const float* __restrict__ bn_vec, const float* __restrict__ ppb,
    const float* __restrict__ bemb, const float* __restrict__ fw,
    const float* __restrict__ fb, float* __restrict__ film)
{
  int n = blockIdx.x, t = threadIdx.x;
  __shared__ float cond[4][84];
  for (int i=t; i<4*84; i+=256) {
    int b = i/84, j = i%84;
    float v;
    if (j < 16) v = bemb[b*16 + j];
    else if (j == 16) { float p = ppb[((size_t)n*4+b)*2+0]; v = fminf(fmaxf(p*(1.f/1023.f),0.f),1.f); }
    else if (j == 17) { float p = ppb[((size_t)n*4+b)*2+1]; v = fminf(fmaxf(p*(1.f/1023.f),0.f),1.f); }
    else if (j == 18) { float p = ppb[((size_t)n*4+b)*2+0]; v = p - rintf(p); }
    else if (j == 19) { float p = ppb[((size_t)n*4+b)*2+1]; v = p - rintf(p); }
    else v = bn_vec[n*64 + (j-20)];
    cond[b][j] = v;
  }
  __syncthreads();
  int b = t >> 6, oc = t & 63;
  float s = fb[oc];
  for (int j=0;j<84;++j) s = fmaf(cond[b][j], fw[oc*84+j], s);
  film[((size_t)n*4+b)*64 + oc] = s;
}

// ---------------------------------------------------------------------------
// final per-map normalization
// ---------------------------------------------------------------------------
__global__ __launch_bounds__(256) void norm_k(float* __restrict__ out,
                                              const float* __restrict__ sums)
{
  int il = blockIdx.x;
  int p = blockIdx.y*256 + threadIdx.x;
  if (p < 961) {
    float inv = 1.f / fmaxf(sums[il], 1e-8f);
    out[(size_t)il*961 + p] *= inv;
  }
}

// ---------------------------------------------------------------------------
extern "C" void kernel_launch(void* const* d_in, const int* in_sizes, int n_in,
                              void* d_out, int out_size, void* d_ws, size_t ws_size,
                              hipStream_t stream)
{
  const float* bott = (const float*)d_in[0];
  const float* vis  = (const float*)d_in[1];
  const float* spv  = (const float*)d_in[2];
  const float* ppb  = (const float*)d_in[3];
  const float* ic1w = (const float*)d_in[4];  const float* ic1b = (const float*)d_in[5];
  const float* ic2w = (const float*)d_in[6];  const float* ic2b = (const float*)d_in[7];
  const float* ic3w = (const float*)d_in[8];  const float* ic3b = (const float*)d_in[9];
  const float* dww  = (const float*)d_in[10]; const float* dwb  = (const float*)d_in[11];
  const float* lnw  = (const float*)d_in[12]; const float* lnb  = (const float*)d_in[13];
  const float* pw1w = (const float*)d_in[14]; const float* pw1b = (const float*)d_in[15];
  const float* pw2w = (const float*)d_in[16]; const float* pw2b = (const float*)d_in[17];
  const float* cgam = (const float*)d_in[18];
  const float* bnpw = (const float*)d_in[19]; const float* bnpb = (const float*)d_in[20];
  const float* bemb = (const float*)d_in[21];
  const float* fw   = (const float*)d_in[22]; const float* fb   = (const float*)d_in[23];
  const float* d1w  = (const float*)d_in[24]; const float* d1b  = (const float*)d_in[25];
  const float* d2w  = (const float*)d_in[26]; const float* d2b  = (const float*)d_in[27];
  const float* d3w  = (const float*)d_in[28]; const float* d3b  = (const float*)d_in[29];
  float* out = (float*)d_out;

  char* ws = (char*)d_ws;

  unsigned short* bwinT = (unsigned short*)(ws);
  unsigned short* dwout = (unsigned short*)(ws + 31719424);
  unsigned short* vwin  = (unsigned short*)(ws);            // 71,368,704 B
  unsigned short* bufI  = (unsigned short*)(ws + 71368704); // 31,490,048 B
  size_t tail = 102858752;

  float* bnv  = (float*)(ws + tail);
  float* sums = (float*)(ws + tail + 131072);
  float* film = (float*)(ws + tail + 139264);
  unsigned short* W1p = (unsigned short*)(ws + tail + 663552);
  unsigned short* W2p = (unsigned short*)(ws + tail + 1187840);
  unsigned short* Wbp = (unsigned short*)(ws + tail + 1712128);
  unsigned short* Pc1 = (unsigned short*)(ws + tail + 1744896);
  unsigned short* Pc2 = (unsigned short*)(ws + tail + 1818624);
  unsigned short* Pc3 = (unsigned short*)(ws + tail + 1892352);
  unsigned short* Pd1 = (unsigned short*)(ws + tail + 1929216);
  unsigned short* Pd2 = (unsigned short*)(ws + tail + 1947648);
  float* dwwT = (float*)(ws + tail + 1966080);

  {
    PackJobs J;
    const float* srcs[8] = {pw1w, pw2w, bnpw, ic1w, ic2w, ic3w, d1w, d2w};
    unsigned short* dsts[8] = {W1p, W2p, Wbp, Pc1, Pc2, Pc3, Pd1, Pd2};
    int ntns[8] = {64,16,4, 4,4,2, 2,2};
    int ntks[8] = {8,32,8, 18,18,18, 9,9};
    int Ks[8]   = {256,1024,256, 64,64,64, 32,32};
    int convs[8]= {0,0,0, 1,1,1, 1,1};
    int base = 0;
    for (int i=0;i<8;++i) {
      J.src[i]=srcs[i]; J.dst[i]=dsts[i]; J.ntn[i]=ntns[i]; J.ntk[i]=ntks[i];
      J.K[i]=Ks[i]; J.conv[i]=convs[i]; J.base[i]=base;
      base += (ntns[i]*ntks[i]*64 + 255)/256;
    }
    packall_k<<<base,256,0,stream>>>(J);
  }
  dwt_k<<<49,256,0,stream>>>(dww, dwwT);

  hipMemsetAsync(ws + tail, 0, 139264, stream);  // bnv + sums

  float gs = 0.f;
  for (int py=0; py<11; ++py) for (int px=0; px<11; ++px) {
    float ly=-1.f+0.2f*py, lx=-1.f+0.2f*px;
    gs += expf(-(lx*lx+ly*ly)/0.32f);
  }
  const float inv_gsum = 1.f/gs;

  // ---- Phase 2: bottleneck path -> bn_vec -> film ----
  dwfused4_k<<<dim3(512,4),256,0,stream>>>(bott, spv, dwwT, dwb, bwinT, dwout);
  cnx_mfma3_k<<<968,512,0,stream>>>(dwout, lnw,lnb, W1p,pw1b, W2p,pw2b, cgam,
                                    bwinT, Wbp, bnpb, bnv, inv_gsum);
  film_k<<<512,256,0,stream>>>(bnv, ppb, bemb, fw, fb, film);

  // ---- Phase 1+3: extract -> conv chain(4-row) -> fused decoder -> norm ----
  extvwin_k<<<dim3(512,5),256,0,stream>>>(vis, spv, vwin);
  convchain4_k<<<dim3(512,8),512,0,stream>>>(vwin, Pc1,ic1b, Pc2,ic2b, Pc3,ic3b, bufI);
  decfused3_k<<<dim3(2048,2),512,0,stream>>>(bufI, Pd1,d1b, Pd2,d2b,
      film, d3w, d3b, out, sums);
  norm_k<<<dim3(2048,4),256,0,stream>>>(out, sums);
}

// Round 18
// 697.606 us; speedup vs baseline: 1.1213x; 1.1213x over previous
//
#include <hip/hip_runtime.h>
#include <hip/hip_bf16.h>
#include <cstdint>
#include <cstddef>
#include <cmath>

#define DEV __device__ __forceinline__

typedef __attribute__((ext_vector_type(8))) short bf16x8;
typedef __attribute__((ext_vector_type(4))) float f32x4;

// Abramowitz-Stegun 7.1.26 erf approx, |abs err| <= 1.5e-7
DEV float erf_fast(float x){
  float ax = fabsf(x);
  float t = __builtin_amdgcn_rcpf(fmaf(0.3275911f, ax, 1.f));
  float p = t*fmaf(t, fmaf(t, fmaf(t, fmaf(t, 1.061405429f, -1.453152027f),
             1.421413741f), -0.284496736f), 0.254829592f);
  float e = __expf(-ax*ax);
  float r = fmaf(-p, e, 1.f);
  return x >= 0.f ? r : -r;
}
DEV float gelu_f(float x){ return 0.5f*x*(1.0f + erf_fast(x*0.7071067811865476f)); }
DEV float softplus_f(float x){ return fmaxf(x,0.f) + log1pf(expf(-fabsf(x))); }
DEV unsigned short f2bf(float x){
  __hip_bfloat16 h = __float2bfloat16(x);
  return reinterpret_cast<unsigned short&>(h);
}
DEV float bf2f(unsigned short h){
  unsigned u = ((unsigned)h) << 16;
  return __uint_as_float(u);
}

// ---------------------------------------------------------------------------
// Combined weight packing: 8 jobs in one launch.
// ---------------------------------------------------------------------------
struct PackJobs {
  const float* src[8];
  unsigned short* dst[8];
  int ntn[8], ntk[8], K[8], conv[8], base[8];
};

__global__ __launch_bounds__(256) void packall_k(PackJobs J)
{
  int blk = blockIdx.x;
  int j = 0;
#pragma unroll
  for (int i=1;i<8;++i) if (blk >= J.base[i]) j = i;
  int tid = (blk - J.base[j])*256 + threadIdx.x;
  const int ntk = J.ntk[j], K = J.K[j];
  int total = J.ntn[j]*ntk*64;
  if (tid >= total) return;
  int lane = tid & 63;
  int f = tid >> 6;
  int kt = f % ntk, nt = f / ntk;
  int row = nt*16 + (lane & 15);
  int k0 = kt*32 + (lane >> 4)*8;
  const float* src = J.src[j];
  unsigned short h[8];
  if (J.conv[j]) {
    const int Cin = K;
#pragma unroll
    for (int q=0;q<8;++q) {
      int k = k0 + q;
      int s = k / Cin;
      int ic = k - s*Cin;
      h[q] = f2bf(src[((size_t)row*Cin + ic)*9 + s]);
    }
  } else {
#pragma unroll
    for (int q=0;q<8;++q) h[q] = f2bf(src[(size_t)row*K + k0 + q]);
  }
  uint4 pk;
  pk.x = (unsigned)h[0] | ((unsigned)h[1]<<16);
  pk.y = (unsigned)h[2] | ((unsigned)h[3]<<16);
  pk.z = (unsigned)h[4] | ((unsigned)h[5]<<16);
  pk.w = (unsigned)h[6] | ((unsigned)h[7]<<16);
  *reinterpret_cast<uint4*>(J.dst[j] + (size_t)tid*8) = pk;
}

// dw weight transpose: wT[k][ch] = w[ch][k]  (49 x 256)
__global__ __launch_bounds__(256) void dwt_k(const float* __restrict__ w,
                                             float* __restrict__ wT)
{
  int k = blockIdx.x;
  int ch = threadIdx.x;
  wT[k*256 + ch] = w[(size_t)ch*49 + k];
}

// ---------------------------------------------------------------------------
// Extract clamped 33x33 vis windows (incl. conv zero ring) -> bf16 NHWC
// ---------------------------------------------------------------------------
__global__ __launch_bounds__(256) void extvwin_k(const float* __restrict__ vis,
                                                 const float* __restrict__ spv,
                                                 unsigned short* __restrict__ vwin)
{
  int il = blockIdx.x;
  int p = blockIdx.y*256 + threadIdx.x;
  if (p >= 1089) return;
  int wy = p/33, wx = p%33;
  unsigned short* dst = vwin + ((size_t)il*1089 + p)*64;
  if (wy==0 || wy==32 || wx==0 || wx==32) {
    uint4 z = {0,0,0,0};
#pragma unroll
    for (int q=0;q<8;++q) *reinterpret_cast<uint4*>(dst + q*8) = z;
    return;
  }
  int cx = (int)rintf(spv[il*2+0]);
  int cy = (int)rintf(spv[il*2+1]);
  int gy = min(max(cy + wy - 16, 0), 1023);
  int gx = min(max(cx + wx - 16, 0), 1023);
  const float* sp = vis + (size_t)gy*1024 + gx;
  unsigned short h[64];
#pragma unroll
  for (int c=0;c<64;++c) h[c] = f2bf(sp[(size_t)c<<20]);
#pragma unroll
  for (int q=0;q<8;++q) {
    uint4 pk;
    pk.x = (unsigned)h[q*8+0] | ((unsigned)h[q*8+1]<<16);
    pk.y = (unsigned)h[q*8+2] | ((unsigned)h[q*8+3]<<16);
    pk.z = (unsigned)h[q*8+4] | ((unsigned)h[q*8+5]<<16);
    pk.w = (unsigned)h[q*8+6] | ((unsigned)h[q*8+7]<<16);
    *reinterpret_cast<uint4*>(dst + q*8) = pk;
  }
}

// ---------------------------------------------------------------------------
// Fused intrinsic conv chain: c1(64->64,gelu) -> c2(64->64,gelu) ->
// c3(64->32, linear), all in LDS with halo recompute. 8-row strips,
// launch_bounds(512,2): VGPR ~92, no spill (empirically verified).
// ---------------------------------------------------------------------------
__global__ __launch_bounds__(512,2) void convchain_k(
    const unsigned short* __restrict__ vwin,
    const unsigned short* __restrict__ Wp1, const float* __restrict__ B1,
    const unsigned short* __restrict__ Wp2, const float* __restrict__ B2,
    const unsigned short* __restrict__ Wp3, const float* __restrict__ B3,
    unsigned short* __restrict__ outI)
{
  const int item = blockIdx.x;
  const int y0 = blockIdx.y*8;
  const int t = threadIdx.x;
  const int w = t>>6, l = t&63, g = l>>4, l15 = l&15;

  __shared__ __align__(16) unsigned short bufIn[462*64];
  __shared__ __align__(16) unsigned short bufC1[396*64];
  unsigned short* bufC2 = bufIn;

  const uint4 z4 = {0,0,0,0};

  for (int u=t; u<396*8; u+=512)
    *reinterpret_cast<uint4*>(bufC1 + u*8) = z4;
  for (int u=t; u<462*8; u+=512) {
    int slot = u & 7;
    int rowi = u >> 3;
    int r = rowi/33;
    int wy = y0 - 2 + r;
    uint4 val = z4;
    if ((unsigned)wy < 33u)
      val = *reinterpret_cast<const uint4*>(
          vwin + ((size_t)item*1089 + wy*33 + (rowi - r*33))*64 + slot*8);
    int ds = slot ^ (rowi & 7);
    *reinterpret_cast<uint4*>(&bufIn[rowi*64 + ds*8]) = val;
  }
  __syncthreads();

  // ---- c1 ----
  {
    int pbase[3], rowB[3]; bool pv[3];
#pragma unroll
    for (int pt=0; pt<3; ++pt) {
      int pd = (w*3+pt)*16 + l15;
      int pc = min(pd, 371);
      int ry = pc/31, rx = pc - ry*31;
      pbase[pt] = ry*33 + rx;
      rowB[pt] = ry*33 + rx + 1;
      int yab = y0 - 2 + ry;
      pv[pt] = (pd < 372) && ((unsigned)yab < 31u);
    }
    f32x4 a1[4][3];
#pragma unroll
    for (int o=0;o<4;++o)
#pragma unroll
      for (int pt=0;pt<3;++pt) a1[o][pt] = (f32x4){0.f,0.f,0.f,0.f};

    for (int kt=0; kt<18; ++kt) {
      int k0 = kt*32 + g*8;
      int s = k0 >> 6;
      int icg = (k0 - (s<<6)) >> 3;
      int roff = (s/3)*33 + (s - (s/3)*3);
      bf16x8 bf[3];
#pragma unroll
      for (int pt=0; pt<3; ++pt) {
        int rowi = pbase[pt] + roff;
        int ds = icg ^ (rowi & 7);
        bf[pt] = *reinterpret_cast<const bf16x8*>(&bufIn[rowi*64 + ds*8]);
      }
#pragma unroll
      for (int o=0; o<4; ++o) {
        bf16x8 af = *reinterpret_cast<const bf16x8*>(Wp1 + ((size_t)(o*18+kt)*64 + l)*8);
#pragma unroll
        for (int pt=0; pt<3; ++pt)
          a1[o][pt] = __builtin_amdgcn_mfma_f32_16x16x32_bf16(af, bf[pt], a1[o][pt], 0,0,0);
      }
    }
#pragma unroll
    for (int o=0; o<4; ++o) {
      float4 bv4 = *reinterpret_cast<const float4*>(B1 + o*16 + g*4);
      int sl = o*2 + (g>>1);
#pragma unroll
      for (int pt=0; pt<3; ++pt) {
        if (!pv[pt]) continue;
        float v0 = gelu_f(a1[o][pt][0] + bv4.x);
        float v1 = gelu_f(a1[o][pt][1] + bv4.y);
        float v2 = gelu_f(a1[o][pt][2] + bv4.z);
        float v3 = gelu_f(a1[o][pt][3] + bv4.w);
        uint2 pk;
        pk.x = (unsigned)f2bf(v0) | ((unsigned)f2bf(v1)<<16);
        pk.y = (unsigned)f2bf(v2) | ((unsigned)f2bf(v3)<<16);
        int phys = sl ^ (rowB[pt] & 7);
        *reinterpret_cast<uint2*>(&bufC1[rowB[pt]*64 + phys*8 + (g&1)*4]) = pk;
      }
    }
  }
  __syncthreads();

  for (int u=t; u<330*8; u+=512)
    *reinterpret_cast<uint4*>(bufC2 + u*8) = z4;
  __syncthreads();

  // ---- c2 ----
  {
    int pbase[3], rowB[3]; bool pv[3];
#pragma unroll
    for (int pt=0; pt<3; ++pt) {
      int pd = (w*3+pt)*16 + l15;
      int pc = min(pd, 309);
      int ry = pc/31, rx = pc - ry*31;
      pbase[pt] = ry*33 + rx;
      rowB[pt] = ry*33 + rx + 1;
      int yab = y0 - 1 + ry;
      pv[pt] = (pd < 310) && ((unsigned)yab < 31u);
    }
    f32x4 a2[4][3];
#pragma unroll
    for (int o=0;o<4;++o)
#pragma unroll
      for (int pt=0;pt<3;++pt) a2[o][pt] = (f32x4){0.f,0.f,0.f,0.f};

    for (int kt=0; kt<18; ++kt) {
      int k0 = kt*32 + g*8;
      int s = k0 >> 6;
      int icg = (k0 - (s<<6)) >> 3;
      int roff = (s/3)*33 + (s - (s/3)*3);
      bf16x8 bf[3];
#pragma unroll
      for (int pt=0; pt<3; ++pt) {
        int rowi = pbase[pt] + roff;
        int ds = icg ^ (rowi & 7);
        bf[pt] = *reinterpret_cast<const bf16x8*>(&bufC1[rowi*64 + ds*8]);
      }
#pragma unroll
      for (int o=0; o<4; ++o) {
        bf16x8 af = *reinterpret_cast<const bf16x8*>(Wp2 + ((size_t)(o*18+kt)*64 + l)*8);
#pragma unroll
        for (int pt=0; pt<3; ++pt)
          a2[o][pt] = __builtin_amdgcn_mfma_f32_16x16x32_bf16(af, bf[pt], a2[o][pt], 0,0,0);
      }
    }
#pragma unroll
    for (int o=0; o<4; ++o) {
      float4 bv4 = *reinterpret_cast<const float4*>(B2 + o*16 + g*4);
      int sl = o*2 + (g>>1);
#pragma unroll
      for (int pt=0; pt<3; ++pt) {
        if (!pv[pt]) continue;
        float v0 = gelu_f(a2[o][pt][0] + bv4.x);
        float v1 = gelu_f(a2[o][pt][1] + bv4.y);
        float v2 = gelu_f(a2[o][pt][2] + bv4.z);
        float v3 = gelu_f(a2[o][pt][3] + bv4.w);
        uint2 pk;
        pk.x = (unsigned)f2bf(v0) | ((unsigned)f2bf(v1)<<16);
        pk.y = (unsigned)f2bf(v2) | ((unsigned)f2bf(v3)<<16);
        int phys = sl ^ (rowB[pt] & 7);
        *reinterpret_cast<uint2*>(&bufC2[rowB[pt]*64 + phys*8 + (g&1)*4]) = pk;
      }
    }
  }
  __syncthreads();

  // ---- c3 ----
  {
    int pbase[2], gpos[2]; bool pv[2];
#pragma unroll
    for (int pt=0; pt<2; ++pt) {
      int pd = (w*2+pt)*16 + l15;
      int pc = min(pd, 247);
      int ry = pc/31, rx = pc - ry*31;
      pbase[pt] = ry*33 + rx;
      gpos[pt] = y0*31 + pd;
      pv[pt] = (pd < 248) && (gpos[pt] < 961);
    }
    f32x4 a3[2][2];
#pragma unroll
    for (int o=0;o<2;++o)
#pragma unroll
      for (int pt=0;pt<2;++pt) a3[o][pt] = (f32x4){0.f,0.f,0.f,0.f};

    for (int kt=0; kt<18; ++kt) {
      int k0 = kt*32 + g*8;
      int s = k0 >> 6;
      int icg = (k0 - (s<<6)) >> 3;
      int roff = (s/3)*33 + (s - (s/3)*3);
      bf16x8 bf[2];
#pragma unroll
      for (int pt=0; pt<2; ++pt) {
        int rowi = pbase[pt] + roff;
        int ds = icg ^ (rowi & 7);
        bf[pt] = *reinterpret_cast<const bf16x8*>(&bufC2[rowi*64 + ds*8]);
      }
#pragma unroll
      for (int o=0; o<2; ++o) {
        bf16x8 af = *reinterpret_cast<const bf16x8*>(Wp3 + ((size_t)(o*18+kt)*64 + l)*8);
#pragma unroll
        for (int pt=0; pt<2; ++pt)
          a3[o][pt] = __builtin_amdgcn_mfma_f32_16x16x32_bf16(af, bf[pt], a3[o][pt], 0,0,0);
      }
    }
#pragma unroll
    for (int o=0; o<2; ++o) {
      float4 bv4 = *reinterpret_cast<const float4*>(B3 + o*16 + g*4);
#pragma unroll
      for (int pt=0; pt<2; ++pt) {
        if (!pv[pt]) continue;
        float v0 = a3[o][pt][0] + bv4.x;
        float v1 = a3[o][pt][1] + bv4.y;
        float v2 = a3[o][pt][2] + bv4.z;
        float v3 = a3[o][pt][3] + bv4.w;
        uint2 pk;
        pk.x = (unsigned)f2bf(v0) | ((unsigned)f2bf(v1)<<16);
        pk.y = (unsigned)f2bf(v2) | ((unsigned)f2bf(v3)<<16);
        *reinterpret_cast<uint2*>(outI + ((size_t)item*961 + gpos[pt])*32 + o*16 + g*4) = pk;
      }
    }
  }
}

// ---------------------------------------------------------------------------
// Fused decoder v3: 16-row strips, 512 threads, channel-major LDS planes,
// FiLM+gelu staging, wave-level sum reduce.
// ---------------------------------------------------------------------------
__global__ __launch_bounds__(512,4) void decfused3_k(
    const unsigned short* __restrict__ intc,
    const unsigned short* __restrict__ Wp1, const float* __restrict__ B1,
    const unsigned short* __restrict__ Wp2, const float* __restrict__ B2,
    const float* __restrict__ film,
    const float* __restrict__ w3, const float* __restrict__ b3,
    float* __restrict__ outf, float* __restrict__ sums)
{
  const int item = blockIdx.x;
  const int y0 = blockIdx.y*16;
  const int t = threadIdx.x;
  const int w = t>>6, l = t&63, g = l>>4, l15 = l&15;

  constexpr int PA = 660;
  constexpr int PB = 594;
  __shared__ __align__(16) unsigned short ldsA[4*PA*8];
  __shared__ __align__(16) unsigned short ldsB[4*PB*8];

  const int sit = item >> 2;
  const float* frow = film + (size_t)item*64;

  for (int u=t; u<4*PB; u+=512)
    *reinterpret_cast<uint4*>(ldsB + u*8) = (uint4){0,0,0,0};

  for (int u=t; u<PA*4; u+=512) {
    int slot = u & 3;
    int rowi = u >> 2;
    int r = rowi/33, col = rowi - r*33;
    int y = y0 + r - 2, x = col - 1;
    uint4 val = {0,0,0,0};
    if ((unsigned)y < 31u && (unsigned)x < 31u) {
      val = *reinterpret_cast<const uint4*>(intc + ((size_t)sit*961 + y*31 + x)*32 + slot*8);
      int c0 = slot*8;
      float4 g0 = *reinterpret_cast<const float4*>(frow + c0);
      float4 g1 = *reinterpret_cast<const float4*>(frow + c0 + 4);
      float4 b0 = *reinterpret_cast<const float4*>(frow + 32 + c0);
      float4 b1 = *reinterpret_cast<const float4*>(frow + 32 + c0 + 4);
      unsigned short x8[8] = {
        (unsigned short)(val.x&0xffff),(unsigned short)(val.x>>16),
        (unsigned short)(val.y&0xffff),(unsigned short)(val.y>>16),
        (unsigned short)(val.z&0xffff),(unsigned short)(val.z>>16),
        (unsigned short)(val.w&0xffff),(unsigned short)(val.w>>16)};
      unsigned short o8[8];
      o8[0]=f2bf(gelu_f(fmaf(bf2f(x8[0]), 1.f+g0.x, b0.x)));
      o8[1]=f2bf(gelu_f(fmaf(bf2f(x8[1]), 1.f+g0.y, b0.y)));
      o8[2]=f2bf(gelu_f(fmaf(bf2f(x8[2]), 1.f+g0.z, b0.z)));
      o8[3]=f2bf(gelu_f(fmaf(bf2f(x8[3]), 1.f+g0.w, b0.w)));
      o8[4]=f2bf(gelu_f(fmaf(bf2f(x8[4]), 1.f+g1.x, b1.x)));
      o8[5]=f2bf(gelu_f(fmaf(bf2f(x8[5]), 1.f+g1.y, b1.y)));
      o8[6]=f2bf(gelu_f(fmaf(bf2f(x8[6]), 1.f+g1.z, b1.z)));
      o8[7]=f2bf(gelu_f(fmaf(bf2f(x8[7]), 1.f+g1.w, b1.w)));
      val.x = (unsigned)o8[0] | ((unsigned)o8[1]<<16);
      val.y = (unsigned)o8[2] | ((unsigned)o8[3]<<16);
      val.z = (unsigned)o8[4] | ((unsigned)o8[5]<<16);
      val.w = (unsigned)o8[6] | ((unsigned)o8[7]<<16);
    }
    *reinterpret_cast<uint4*>(&ldsA[((size_t)slot*PA + rowi)*8]) = val;
  }
  __syncthreads();

  // ---- dec1 ----
  {
    int pbase[5], rowB[5]; bool pv[5];
#pragma unroll
    for (int pt=0; pt<5; ++pt) {
      int pd = (w*5+pt)*16 + l15;
      int pc = min(pd, 557);
      int ry = pc/31, rx = pc - ry*31;
      pbase[pt] = ry*33 + rx;
      rowB[pt] = ry*33 + rx + 1;
      int gy = y0 - 1 + ry;
      pv[pt] = (pd < 558) && ((unsigned)gy < 31u);
    }
    f32x4 a1[2][5];
#pragma unroll
    for (int o=0;o<2;++o)
#pragma unroll
      for (int pt=0;pt<5;++pt) a1[o][pt] = (f32x4){0.f,0.f,0.f,0.f};

    for (int kt=0; kt<9; ++kt) {
      int roff = (kt/3)*33 + (kt - (kt/3)*3);
      bf16x8 bf[5];
#pragma unroll
      for (int pt=0; pt<5; ++pt) {
        int rowi = pbase[pt] + roff;
        bf[pt] = *reinterpret_cast<const bf16x8*>(&ldsA[((size_t)g*PA + rowi)*8]);
      }
#pragma unroll
      for (int o=0; o<2; ++o) {
        bf16x8 af = *reinterpret_cast<const bf16x8*>(Wp1 + ((size_t)(o*9+kt)*64 + l)*8);
#pragma unroll
        for (int pt=0; pt<5; ++pt)
          a1[o][pt] = __builtin_amdgcn_mfma_f32_16x16x32_bf16(af, bf[pt], a1[o][pt], 0,0,0);
      }
    }
#pragma unroll
    for (int o=0; o<2; ++o) {
      float4 bv4 = *reinterpret_cast<const float4*>(B1 + o*16 + g*4);
      int sl = o*2 + (g>>1);
#pragma unroll
      for (int pt=0; pt<5; ++pt) {
        if (!pv[pt]) continue;
        float v0 = gelu_f(a1[o][pt][0] + bv4.x);
        float v1 = gelu_f(a1[o][pt][1] + bv4.y);
        float v2 = gelu_f(a1[o][pt][2] + bv4.z);
        float v3 = gelu_f(a1[o][pt][3] + bv4.w);
        uint2 pk;
        pk.x = (unsigned)f2bf(v0) | ((unsigned)f2bf(v1)<<16);
        pk.y = (unsigned)f2bf(v2) | ((unsigned)f2bf(v3)<<16);
        *reinterpret_cast<uint2*>(&ldsB[((size_t)sl*PB + rowB[pt])*8 + (g&1)*4]) = pk;
      }
    }
  }
  __syncthreads();

  // ---- dec2 + gelu + dec3(1x1) + softplus + per-map sum ----
  float bsum = 0.f;
  {
    int pbase[4], gpos[4]; bool pv[4];
#pragma unroll
    for (int pt=0; pt<4; ++pt) {
      int pd = (w*4+pt)*16 + l15;
      int pc = min(pd, 495);
      int py = pc/31, px = pc - py*31;
      pbase[pt] = py*33 + px;
      gpos[pt] = y0*31 + pd;
      pv[pt] = (pd < 496) && (gpos[pt] < 961);
    }
    f32x4 a2[2][4];
#pragma unroll
    for (int o=0;o<2;++o)
#pragma unroll
      for (int pt=0;pt<4;++pt) a2[o][pt] = (f32x4){0.f,0.f,0.f,0.f};

    for (int kt=0; kt<9; ++kt) {
      int roff = (kt/3)*33 + (kt - (kt/3)*3);
      bf16x8 bf[4];
#pragma unroll
      for (int pt=0; pt<4; ++pt) {
        int rowi = pbase[pt] + roff;
        bf[pt] = *reinterpret_cast<const bf16x8*>(&ldsB[((size_t)g*PB + rowi)*8]);
      }
#pragma unroll
      for (int o=0; o<2; ++o) {
        bf16x8 af = *reinterpret_cast<const bf16x8*>(Wp2 + ((size_t)(o*9+kt)*64 + l)*8);
#pragma unroll
        for (int pt=0; pt<4; ++pt)
          a2[o][pt] = __builtin_amdgcn_mfma_f32_16x16x32_bf16(af, bf[pt], a2[o][pt], 0,0,0);
      }
    }

    float w3r[8];
#pragma unroll
    for (int o=0;o<2;++o) {
      float4 wv = *reinterpret_cast<const float4*>(w3 + o*16 + g*4);
      w3r[o*4+0]=wv.x; w3r[o*4+1]=wv.y; w3r[o*4+2]=wv.z; w3r[o*4+3]=wv.w;
    }
    float b3v = b3[0];
#pragma unroll
    for (int pt=0; pt<4; ++pt) {
      float part = 0.f;
#pragma unroll
      for (int o=0; o<2; ++o) {
        float4 bv4 = *reinterpret_cast<const float4*>(B2 + o*16 + g*4);
        float v0 = gelu_f(a2[o][pt][0] + bv4.x);
        float v1 = gelu_f(a2[o][pt][1] + bv4.y);
        float v2 = gelu_f(a2[o][pt][2] + bv4.z);
        float v3 = gelu_f(a2[o][pt][3] + bv4.w);
        part += v0*w3r[o*4+0] + v1*w3r[o*4+1] + v2*w3r[o*4+2] + v3*w3r[o*4+3];
      }
      part += __shfl_xor(part, 16);
      part += __shfl_xor(part, 32);
      float sp = softplus_f(part + b3v);
      if (pv[pt] && g==0) {
        outf[(size_t)item*961 + gpos[pt]] = sp;
        bsum += sp;
      }
    }
  }
  bsum += __shfl_xor(bsum, 1);
  bsum += __shfl_xor(bsum, 2);
  bsum += __shfl_xor(bsum, 4);
  bsum += __shfl_xor(bsum, 8);
  bsum += __shfl_xor(bsum, 16);
  bsum += __shfl_xor(bsum, 32);
  if (l == 0) atomicAdd(&sums[item], bsum);
}

// ---------------------------------------------------------------------------
// Fused bottleneck-window gather + depthwise 7x7, channel-sliced, row-reuse.
// ---------------------------------------------------------------------------
__global__ __launch_bounds__(256,4) void dwfused4_k(
    const float* __restrict__ bott, const float* __restrict__ spv,
    const float* __restrict__ wT, const float* __restrict__ b,
    unsigned short* __restrict__ bwinT, unsigned short* __restrict__ dwout)
{
  const int n = blockIdx.x, cs = blockIdx.y*64, t = threadIdx.x;
  __shared__ float tile[121*66];

  float pxf = fminf(fmaxf(spv[n*2+0]*0.25f, 0.f), 255.f);
  float pyf = fminf(fmaxf(spv[n*2+1]*0.25f, 0.f), 255.f);
  int cx = (int)rintf(pxf), cy = (int)rintf(pyf);

  for (int idx=t; idx<121*32; idx+=256) {
    int j = idx/121, p = idx - j*121;
    int y = p/11, x = p - y*11;
    int gy = min(max(cy + y - 5, 0), 255);
    int gx = min(max(cx + x - 5, 0), 255);
    const float* s0 = bott + ((size_t)(cs+2*j)<<16) + (gy<<8) + gx;
    *reinterpret_cast<float2*>(&tile[p*66 + 2*j]) = (float2){s0[0], s0[65536]};
  }
  __syncthreads();

  for (int idx=t; idx<121*64; idx+=256) {
    int p = idx >> 6, c = idx & 63;
    bwinT[((size_t)n*121 + p)*256 + cs + c] = f2bf(tile[p*66 + c]);
  }

  const int c = t & 63, ph = t >> 6;
  const int ch = cs + c;
  const float bias = b[ch];

  for (int y=ph; y<11; y+=4) {
    float acc[11];
#pragma unroll
    for (int x=0;x<11;++x) acc[x] = bias;
#pragma unroll
    for (int dy=0; dy<7; ++dy) {
      int yy = y + dy - 3;
      if ((unsigned)yy < 11u) {
        float r[11];
#pragma unroll
        for (int k=0;k<11;++k) r[k] = tile[(yy*11+k)*66 + c];
        float w7[7];
#pragma unroll
        for (int j=0;j<7;++j) w7[j] = wT[(dy*7+j)*256 + ch];
#pragma unroll
        for (int x=0;x<11;++x) {
#pragma unroll
          for (int dx=0;dx<7;++dx) {
            int xx = x + dx - 3;
            if (xx >= 0 && xx < 11)
              acc[x] = fmaf(r[xx], w7[dx], acc[x]);
          }
        }
      }
    }
#pragma unroll
    for (int x=0;x<11;++x)
      dwout[((size_t)n*121 + y*11 + x)*256 + ch] = f2bf(acc[x]);
  }
}

// ---------------------------------------------------------------------------
// Fused ConvNeXt MLP + bnp head, bf16 MFMA. 512 threads / 8 waves, 64 rows.
// ---------------------------------------------------------------------------
__global__ __launch_bounds__(512,4) void cnx_mfma3_k(
    const unsigned short* __restrict__ xin,
    const float* __restrict__ lnw, const float* __restrict__ lnb,
    const unsigned short* __restrict__ W1p, const float* __restrict__ B1,
    const unsigned short* __restrict__ W2p, const float* __restrict__ B2,
    const float* __restrict__ gvec,
    const unsigned short* __restrict__ bwinT,
    const unsigned short* __restrict__ Wbp, const float* __restrict__ bnpb,
    float* __restrict__ bnv, float inv_gsum)
{
  const int t = threadIdx.x;
  const int w = t >> 6;
  const int l = t & 63;
  const int g = l >> 4;
  const int l15 = l & 15;
  const int row0 = blockIdx.x * 64;

  __shared__ __align__(16) unsigned short xs[64*264];
  __shared__ __align__(16) unsigned short hs[64*136];

  {
    const int rl = t >> 3, q = t & 7;
    const unsigned short* xr = xin + (size_t)(row0+rl)*256 + q*32;
    float xv[32]; float s = 0.f, s2 = 0.f;
#pragma unroll
    for (int i=0;i<32;i+=8){
      uint4 v = *reinterpret_cast<const uint4*>(xr+i);
      unsigned short xh[8] = {
        (unsigned short)(v.x&0xffff),(unsigned short)(v.x>>16),
        (unsigned short)(v.y&0xffff),(unsigned short)(v.y>>16),
        (unsigned short)(v.z&0xffff),(unsigned short)(v.z>>16),
        (unsigned short)(v.w&0xffff),(unsigned short)(v.w>>16)};
#pragma unroll
      for (int j=0;j<8;++j){
        float f = bf2f(xh[j]);
        xv[i+j] = f; s += f; s2 += f*f;
      }
    }
    s += __shfl_xor(s,1); s2 += __shfl_xor(s2,1);
    s += __shfl_xor(s,2); s2 += __shfl_xor(s2,2);
    s += __shfl_xor(s,4); s2 += __shfl_xor(s2,4);
    float mu = s*(1.f/256.f);
    float rstd = rsqrtf(s2*(1.f/256.f) - mu*mu + 1e-6f);
#pragma unroll
    for (int i=0;i<32;i+=8){
      int c = q*32 + i;
      float4 w0 = *reinterpret_cast<const float4*>(lnw+c);
      float4 w1 = *reinterpret_cast<const float4*>(lnw+c+4);
      float4 b0 = *reinterpret_cast<const float4*>(lnb+c);
      float4 b1 = *reinterpret_cast<const float4*>(lnb+c+4);
      unsigned short h[8];
      h[0]=f2bf(fmaf((xv[i+0]-mu)*rstd, w0.x, b0.x));
      h[1]=f2bf(fmaf((xv[i+1]-mu)*rstd, w0.y, b0.y));
      h[2]=f2bf(fmaf((xv[i+2]-mu)*rstd, w0.z, b0.z));
      h[3]=f2bf(fmaf((xv[i+3]-mu)*rstd, w0.w, b0.w));
      h[4]=f2bf(fmaf((xv[i+4]-mu)*rstd, w1.x, b1.x));
      h[5]=f2bf(fmaf((xv[i+5]-mu)*rstd, w1.y, b1.y));
      h[6]=f2bf(fmaf((xv[i+6]-mu)*rstd, w1.z, b1.z));
      h[7]=f2bf(fmaf((xv[i+7]-mu)*rstd, w1.w, b1.w));
      uint4 pk;
      pk.x = (unsigned)h[0] | ((unsigned)h[1]<<16);
      pk.y = (unsigned)h[2] | ((unsigned)h[3]<<16);
      pk.z = (unsigned)h[4] | ((unsigned)h[5]<<16);
      pk.w = (unsigned)h[6] | ((unsigned)h[7]<<16);
      *reinterpret_cast<uint4*>(&xs[rl*264 + c]) = pk;
    }
  }
  __syncthreads();

  f32x4 acc2[8];
#pragma unroll
  for (int i=0;i<8;++i) acc2[i] = (f32x4){0.f,0.f,0.f,0.f};

  for (int hc=0; hc<8; ++hc) {
    const int ht = hc*8 + w;
    f32x4 acc1[4];
#pragma unroll
    for (int i=0;i<4;++i) acc1[i] = (f32x4){0.f,0.f,0.f,0.f};

#pragma unroll
    for (int kt=0; kt<8; ++kt) {
      bf16x8 xf[4];
#pragma unroll
      for (int rt=0; rt<4; ++rt)
        xf[rt] = *reinterpret_cast<const bf16x8*>(&xs[(rt*16+l15)*264 + kt*32 + g*8]);
      bf16x8 wf = *reinterpret_cast<const bf16x8*>(W1p + ((size_t)(ht*8+kt)*64 + l)*8);
#pragma unroll
      for (int rt=0; rt<4; ++rt)
        acc1[rt] = __builtin_amdgcn_mfma_f32_16x16x32_bf16(wf, xf[rt], acc1[rt], 0,0,0);
    }
    {
      const int hb = hc*128 + w*16 + 4*g;
      float4 b1v = *reinterpret_cast<const float4*>(B1 + hb);
#pragma unroll
      for (int rt=0; rt<4; ++rt) {
        unsigned short h0 = f2bf(gelu_f(acc1[rt][0] + b1v.x));
        unsigned short h1 = f2bf(gelu_f(acc1[rt][1] + b1v.y));
        unsigned short h2 = f2bf(gelu_f(acc1[rt][2] + b1v.z));
        unsigned short h3 = f2bf(gelu_f(acc1[rt][3] + b1v.w));
        uint2 pk;
        pk.x = (unsigned)h0 | ((unsigned)h1<<16);
        pk.y = (unsigned)h2 | ((unsigned)h3<<16);
        *reinterpret_cast<uint2*>(&hs[(rt*16+l15)*136 + w*16 + 4*g]) = pk;
      }
    }
    __syncthreads();
#pragma unroll
    for (int kt=0; kt<4; ++kt) {
      bf16x8 hf[4];
#pragma unroll
      for (int rt=0; rt<4; ++rt)
        hf[rt] = *reinterpret_cast<const bf16x8*>(&hs[(rt*16+l15)*136 + kt*32 + g*8]);
#pragma unroll
      for (int cj=0; cj<2; ++cj) {
        const int ct = 2*w + cj;
        bf16x8 wf = *reinterpret_cast<const bf16x8*>(W2p + ((size_t)(ct*32 + hc*4 + kt)*64 + l)*8);
#pragma unroll
        for (int rt=0; rt<4; ++rt)
          acc2[cj*4+rt] = __builtin_amdgcn_mfma_f32_16x16x32_bf16(hf[rt], wf, acc2[cj*4+rt], 0,0,0);
      }
    }
    __syncthreads();
  }

#pragma unroll
  for (int cj=0; cj<2; ++cj) {
    const int c = (2*w+cj)*16 + l15;
    const float b2 = B2[c], gm = gvec[c];
#pragma unroll
    for (int rt=0; rt<4; ++rt) {
#pragma unroll
      for (int reg=0; reg<4; ++reg) {
        int row = rt*16 + 4*g + reg;
        float res = bf2f(bwinT[(size_t)(row0+row)*256 + c]) + (acc2[cj*4+rt][reg] + b2)*gm;
        xs[row*264 + c] = f2bf(res);
      }
    }
  }
  __syncthreads();

  {
    const int oct = w & 3;
    f32x4 abn[2];
#pragma unroll
    for (int i=0;i<2;++i) abn[i] = (f32x4){0.f,0.f,0.f,0.f};
#pragma unroll
    for (int kt=0; kt<8; ++kt) {
      bf16x8 bfw = *reinterpret_cast<const bf16x8*>(Wbp + ((size_t)(oct*8+kt)*64 + l)*8);
#pragma unroll
      for (int i=0;i<2;++i) {
        const int rt = (w>>2) + 2*i;
        bf16x8 af = *reinterpret_cast<const bf16x8*>(&xs[(rt*16+l15)*264 + kt*32 + g*8]);
        abn[i] = __builtin_amdgcn_mfma_f32_16x16x32_bf16(af, bfw, abn[i], 0,0,0);
      }
    }

    float* red = reinterpret_cast<float*>(hs);
#pragma unroll
    for (int i=0;i<2;++i) {
      const int rt = (w>>2) + 2*i;
      float bv = bnpb[oct*16 + l15];
#pragma unroll
      for (int reg=0; reg<4; ++reg) {
        int lr = rt*16 + g*4 + reg;
        int p = (row0 + lr) % 121;
        int py=p/11, px=p-py*11;
        float ly=-1.f+0.2f*py, lx=-1.f+0.2f*px;
        float wg = __expf(-(lx*lx+ly*ly)/0.32f) * inv_gsum;
        red[lr*64 + oct*16 + l15] = gelu_f(abn[i][reg] + bv) * wg;
      }
    }
  }
  __syncthreads();
  {
    float* red = reinterpret_cast<float*>(hs);
    int oc = t & 63, seg = t >> 6;
    float s = 0.f;
    int curn = (row0 + seg*8) / 121;
    for (int i=0;i<8;++i) {
      int row = seg*8 + i;
      int n = (row0 + row) / 121;
      if (n != curn) { atomicAdd(&bnv[curn*64 + oc], s); s = 0.f; curn = n; }
      s += red[row*64 + oc];
    }
    atomicAdd(&bnv[curn*64 + oc], s);
  }
}

// ---------------------------------------------------------------------------
// FiLM
// ---------------------------------------------------------------------------
__global__ __launch_bounds__(256) void film_k(
    const float* __restrict__ bn_vec, const float* __restrict__ ppb,
    const float* __restrict__ bemb, const float* __restrict__ fw,
    const float* __restrict__ fb, float* __restrict__ film)
{
  int n = blockIdx.x, t = threadIdx.x;
  __shared__ float cond[4][84];
  for (int i=t; i<4*84; i+=256) {
    int b = i/84, j = i%84;
    float v;
    if (j < 16) v = bemb[b*16 + j];
    else if (j == 16) { float p = ppb[((size_t)n*4+b)*2+0]; v = fminf(fmaxf(p*(1.f/1023.f),0.f),1.f); }
    else if (j == 17) { float p = ppb[((size_t)n*4+b)*2+1]; v = fminf(fmaxf(p*(1.f/1023.f),0.f),1.f); }
    else if (j == 18) { float p = ppb[((size_t)n*4+b)*2+0]; v = p - rintf(p); }
    else if (j == 19) { float p = ppb[((size_t)n*4+b)*2+1]; v = p - rintf(p); }
    else v = bn_vec[n*64 + (j-20)];
    cond[b][j] = v;
  }
  __syncthreads();
  int b = t >> 6, oc = t & 63;
  float s = fb[oc];
  for (int j=0;j<84;++j) s = fmaf(cond[b][j], fw[oc*84+j], s);
  film[((size_t)n*4+b)*64 + oc] = s;
}

// ---------------------------------------------------------------------------
// final per-map normalization
// ---------------------------------------------------------------------------
__global__ __launch_bounds__(256) void norm_k(float* __restrict__ out,
                                              const float* __restrict__ sums)
{
  int il = blockIdx.x;
  int p = blockIdx.y*256 + threadIdx.x;
  if (p < 961) {
    float inv = 1.f / fmaxf(sums[il], 1e-8f);
    out[(size_t)il*961 + p] *= inv;
  }
}

// ---------------------------------------------------------------------------
extern "C" void kernel_launch(void* const* d_in, const int* in_sizes, int n_in,
                              void* d_out, int out_size, void* d_ws, size_t ws_size,
                              hipStream_t stream)
{
  const float* bott = (const float*)d_in[0];
  const float* vis  = (const float*)d_in[1];
  const float* spv  = (const float*)d_in[2];
  const float* ppb  = (const float*)d_in[3];
  const float* ic1w = (const float*)d_in[4];  const float* ic1b = (const float*)d_in[5];
  const float* ic2w = (const float*)d_in[6];  const float* ic2b = (const float*)d_in[7];
  const float* ic3w = (const float*)d_in[8];  const float* ic3b = (const float*)d_in[9];
  const float* dww  = (const float*)d_in[10]; const float* dwb  = (const float*)d_in[11];
  const float* lnw  = (const float*)d_in[12]; const float* lnb  = (const float*)d_in[13];
  const float* pw1w = (const float*)d_in[14]; const float* pw1b = (const float*)d_in[15];
  const float* pw2w = (const float*)d_in[16]; const float* pw2b = (const float*)d_in[17];
  const float* cgam = (const float*)d_in[18];
  const float* bnpw = (const float*)d_in[19]; const float* bnpb = (const float*)d_in[20];
  const float* bemb = (const float*)d_in[21];
  const float* fw   = (const float*)d_in[22]; const float* fb   = (const float*)d_in[23];
  const float* d1w  = (const float*)d_in[24]; const float* d1b  = (const float*)d_in[25];
  const float* d2w  = (const float*)d_in[26]; const float* d2b  = (const float*)d_in[27];
  const float* d3w  = (const float*)d_in[28]; const float* d3b  = (const float*)d_in[29];
  float* out = (float*)d_out;

  char* ws = (char*)d_ws;

  unsigned short* bwinT = (unsigned short*)(ws);
  unsigned short* dwout = (unsigned short*)(ws + 31719424);
  unsigned short* vwin  = (unsigned short*)(ws);            // 71,368,704 B
  unsigned short* bufI  = (unsigned short*)(ws + 71368704); // 31,490,048 B
  size_t tail = 102858752;

  float* bnv  = (float*)(ws + tail);
  float* sums = (float*)(ws + tail + 131072);
  float* film = (float*)(ws + tail + 139264);
  unsigned short* W1p = (unsigned short*)(ws + tail + 663552);
  unsigned short* W2p = (unsigned short*)(ws + tail + 1187840);
  unsigned short* Wbp = (unsigned short*)(ws + tail + 1712128);
  unsigned short* Pc1 = (unsigned short*)(ws + tail + 1744896);
  unsigned short* Pc2 = (unsigned short*)(ws + tail + 1818624);
  unsigned short* Pc3 = (unsigned short*)(ws + tail + 1892352);
  unsigned short* Pd1 = (unsigned short*)(ws + tail + 1929216);
  unsigned short* Pd2 = (unsigned short*)(ws + tail + 1947648);
  float* dwwT = (float*)(ws + tail + 1966080);

  {
    PackJobs J;
    const float* srcs[8] = {pw1w, pw2w, bnpw, ic1w, ic2w, ic3w, d1w, d2w};
    unsigned short* dsts[8] = {W1p, W2p, Wbp, Pc1, Pc2, Pc3, Pd1, Pd2};
    int ntns[8] = {64,16,4, 4,4,2, 2,2};
    int ntks[8] = {8,32,8, 18,18,18, 9,9};
    int Ks[8]   = {256,1024,256, 64,64,64, 32,32};
    int convs[8]= {0,0,0, 1,1,1, 1,1};
    int base = 0;
    for (int i=0;i<8;++i) {
      J.src[i]=srcs[i]; J.dst[i]=dsts[i]; J.ntn[i]=ntns[i]; J.ntk[i]=ntks[i];
      J.K[i]=Ks[i]; J.conv[i]=convs[i]; J.base[i]=base;
      base += (ntns[i]*ntks[i]*64 + 255)/256;
    }
    packall_k<<<base,256,0,stream>>>(J);
  }
  dwt_k<<<49,256,0,stream>>>(dww, dwwT);

  hipMemsetAsync(ws + tail, 0, 139264, stream);  // bnv + sums

  float gs = 0.f;
  for (int py=0; py<11; ++py) for (int px=0; px<11; ++px) {
    float ly=-1.f+0.2f*py, lx=-1.f+0.2f*px;
    gs += expf(-(lx*lx+ly*ly)/0.32f);
  }
  const float inv_gsum = 1.f/gs;

  // ---- Phase 2: bottleneck path -> bn_vec -> film ----
  dwfused4_k<<<dim3(512,4),256,0,stream>>>(bott, spv, dwwT, dwb, bwinT, dwout);
  cnx_mfma3_k<<<968,512,0,stream>>>(dwout, lnw,lnb, W1p,pw1b, W2p,pw2b, cgam,
                                    bwinT, Wbp, bnpb, bnv, inv_gsum);
  film_k<<<512,256,0,stream>>>(bnv, ppb, bemb, fw, fb, film);

  // ---- Phase 1+3: extract -> conv chain -> fused decoder -> norm ----
  extvwin_k<<<dim3(512,5),256,0,stream>>>(vis, spv, vwin);
  convchain_k<<<dim3(512,4),512,0,stream>>>(vwin, Pc1,ic1b, Pc2,ic2b, Pc3,ic3b, bufI);
  decfused3_k<<<dim3(2048,2),512,0,stream>>>(bufI, Pd1,d1b, Pd2,d2b,
      film, d3w, d3b, out, sums);
  norm_k<<<dim3(2048,4),256,0,stream>>>(out, sums);
}